// Round 3
// baseline (400.511 us; speedup 1.0000x reference)
//
#include <hip/hip_runtime.h>
#include <hip/hip_bf16.h>
#include <math.h>

#define B    512
#define INU  8
#define IC   1152
#define NU   10
#define US   16
#define JU   160            // NU*US
#define KI   9216           // INU*IC
#define BETAC 1.45f
#define NSPLIT 32
#define KC 288              // KI / NSPLIT; divides IC

typedef __attribute__((ext_vector_type(8))) __bf16 bf16x8;
typedef __attribute__((ext_vector_type(4))) float floatx4;

static __device__ __forceinline__ unsigned short f2bf(float f) {
  unsigned u = __builtin_bit_cast(unsigned, f);
  u = (u + 0x7fffu + ((u >> 16) & 1u)) >> 16;   // RNE
  return (unsigned short)u;
}
static __device__ __forceinline__ float bf2f(unsigned short h) {
  return __builtin_bit_cast(float, ((unsigned)h) << 16);
}
// 8 bf16 * 8 fp32 scale -> 8 bf16 (packed RNE converts)
static __device__ __forceinline__ uint4 scale8(uint4 wv, float4 cA, float4 cB) {
  union { uint4 u; unsigned short s[8]; } in;
  in.u = wv;
  union { uint4 u; __hip_bfloat162 h[4]; } o;
  o.h[0] = __float22bfloat162_rn(make_float2(bf2f(in.s[0]) * cA.x, bf2f(in.s[1]) * cA.y));
  o.h[1] = __float22bfloat162_rn(make_float2(bf2f(in.s[2]) * cA.z, bf2f(in.s[3]) * cA.w));
  o.h[2] = __float22bfloat162_rn(make_float2(bf2f(in.s[4]) * cB.x, bf2f(in.s[5]) * cB.y));
  o.h[3] = __float22bfloat162_rn(make_float2(bf2f(in.s[6]) * cB.z, bf2f(in.s[7]) * cB.w));
  return o.u;
}

// ---------------------------------------------------------------------------
// prep (one-time): blocks [0,1152): x -> xb bf16 [b][ki] + xT bf16 [ki][b]
// (64x64 LDS transpose). blocks [1152,1296): W LDS-tiled -> Wt bf16 [ju][ki]
// (MFMA B layout) + Wc = Wt * (1/IC) (iteration-0 scaled weights) + Wr fp32
// [ki][ju] (coalesced epilogue reads). Block 0 zeroes the grid-barrier ctr.
// ---------------------------------------------------------------------------
__global__ __launch_bounds__(256) void prep_kernel(
    const float* __restrict__ x, const float* __restrict__ W,
    unsigned short* __restrict__ xb, unsigned short* __restrict__ xT,
    unsigned short* __restrict__ Wt, unsigned short* __restrict__ Wc,
    float* __restrict__ Wr, int* __restrict__ gbar) {
  __shared__ float ts[32 * 322];    // 41.2 KB (x-part uses first 64*65)
  int id = blockIdx.x;
  int t = threadIdx.x;
  if (id == 0 && t == 0) *gbar = 0;   // re-zero every launch (ws is poisoned)
  if (id < 1152) {
    int k0 = (id % 144) * 64;
    int b0 = (id / 144) * 64;
#pragma unroll
    for (int r = 0; r < 16; ++r) {
      int idx = t + 256 * r;
      int br = idx >> 6, kc = idx & 63;
      float v = x[(size_t)(b0 + br) * KI + k0 + kc];
      ts[br * 65 + kc] = v;
      xb[(size_t)(b0 + br) * KI + k0 + kc] = f2bf(v);
    }
    __syncthreads();
#pragma unroll
    for (int r = 0; r < 8; ++r) {
      int idx = t + 256 * r;            // 0..2047
      int kr = idx >> 5, bc = (idx & 31) * 2;
      unsigned lo = f2bf(ts[bc * 65 + kr]);
      unsigned hi = f2bf(ts[(bc + 1) * 65 + kr]);
      *(unsigned*)&xT[(size_t)(k0 + kr) * B + b0 + bc] = lo | (hi << 16);
    }
  } else {
    int wid = id - 1152;              // 0..143
    int i0 = (wid >> 2) * 32;         // 36 i-chunks
    int c0 = (wid & 3) * 320;         // 4 c-chunks of W's 1280-wide rows
#pragma unroll
    for (int r = 0; r < 20; ++r) {
      int q = t + 256 * r;            // < 5120 float2
      int il = q / 160, c = (q - il * 160) * 2;
      *(float2*)&ts[il * 322 + c] =
          *(const float2*)&W[(size_t)(i0 + il) * 1280 + c0 + c];
    }
    __syncthreads();
    {
      const float cinv = 1.0f / (float)IC;
      int il2 = (t & 15) * 2;
      for (int p = (t >> 4); p < 320; p += 16) {
        int c = c0 + p;
        int ju = c >> 3, k = c & 7;
        unsigned lo = f2bf(ts[il2 * 322 + p]);
        unsigned hi = f2bf(ts[(il2 + 1) * 322 + p]);
        *(unsigned*)&Wt[(size_t)ju * KI + k * IC + i0 + il2] = lo | (hi << 16);
        unsigned lo2 = f2bf(bf2f((unsigned short)lo) * cinv);
        unsigned hi2 = f2bf(bf2f((unsigned short)hi) * cinv);
        *(unsigned*)&Wc[(size_t)ju * KI + k * IC + i0 + il2] = lo2 | (hi2 << 16);
      }
    }
    int ju0 = c0 >> 3;
    for (int q = t; q < 8 * 32 * 40; q += 256) {
      int k = q / 1280;
      int il = (q / 40) & 31;
      int jl = q - (q / 40) * 40;
      Wr[((size_t)k * IC + i0 + il) * JU + ju0 + jl] = ts[il * 322 + jl * 8 + k];
    }
  }
}

// ---------------------------------------------------------------------------
// routing_kernel (persistent, NORMAL launch): full 3-iteration routing loop.
// Grid: 256 blocks x 256 threads. Co-residency by capacity: 35.9 KB LDS and
// 4 waves/block => >=4 blocks/CU possible, so all 256 blocks are resident
// under any dispatch placement -> hand-rolled grid barrier cannot deadlock.
// Barrier: monotonic counter, device-scope fences both sides (per-XCD L2s
// are not coherent; __threadfence gives the agent-scope wb/inv).
// Phases (bodies identical to the round-1 standalone kernels):
//   G: sp[y][b][ju] = sum_{ki in chunk y} xb[b,ki]*Wc[ju,ki]  (256 items)
//   S: squash -> vT (and out on it==2)                        (512 items, 2/blk)
//   U: R = xT*vT^T; bp = (1/B) sum_u Wr*R                     (288 items, strided)
//   C: softmax_i(sum_p bp) -> fold into Wc = Wt * c           (160 items)
// ---------------------------------------------------------------------------
__global__ __launch_bounds__(256) void routing_kernel(
    const unsigned short* __restrict__ xb, const unsigned short* __restrict__ xT,
    const unsigned short* __restrict__ Wt, unsigned short* __restrict__ Wc,
    const float* __restrict__ Wr, float* __restrict__ sp,
    unsigned short* __restrict__ vT, float* __restrict__ bp,
    float* __restrict__ out, int* __restrict__ gbar) {
  __shared__ uint4 smem4[35840 / 16];   // 35.84 KB, max over phases
  unsigned short* xs = (unsigned short*)smem4;                 // [2][64*40]
  unsigned short* ms = (unsigned short*)((char*)smem4 + 10240);// [2][160*40]
  float* c_sh = (float*)smem4;                                 // softmax: [IC]
  float* red  = (float*)((char*)smem4 + IC * 4);               // [256]
  float* sv   = (float*)smem4;                                 // squash: [JU]
  float* fac  = (float*)((char*)smem4 + JU * 4);               // [US]

  const int t = threadIdx.x;
  const int w = t >> 6, lane = t & 63, col = lane & 15, quad = lane >> 4;
  const int xrow = t >> 2, xc = (t & 3) * 8;
  const int mrow0 = t >> 2, mrow1 = (t + 256) >> 2, mrow2 = (t + 512) >> 2;
  const int mc = (t & 3) * 8;

  int barg = 0;
  auto gsync = [&]() {
    ++barg;
    __syncthreads();                 // all block stores drained (vmcnt at barrier)
    if (t == 0) {
      __threadfence();               // release: agent-scope wb (cross-XCD visible)
      __hip_atomic_fetch_add(gbar, 1, __ATOMIC_RELAXED, __HIP_MEMORY_SCOPE_AGENT);
      while (__hip_atomic_load(gbar, __ATOMIC_RELAXED, __HIP_MEMORY_SCOPE_AGENT) <
             barg * 256)
        __builtin_amdgcn_s_sleep(2);
      __threadfence();               // acquire: invalidate L1/L2 before reads
    }
    __syncthreads();
  };

  for (int it = 0; it < 3; ++it) {
    // ---- phase G: s-GEMM (item = blockIdx.x, exactly 256 items) ----
    {
      const int b0 = (blockIdx.x & 7) * 64;
      const int kbase = (blockIdx.x >> 3) * KC;
      uint4 xv, m0, m1, m2;
      auto prefetch = [&](int k0) {
        xv = *(const uint4*)&xb[(size_t)(b0 + xrow) * KI + k0 + xc];
        m0 = *(const uint4*)&Wc[(size_t)mrow0 * KI + k0 + mc];
        m1 = *(const uint4*)&Wc[(size_t)mrow1 * KI + k0 + mc];
        if (t < 128) m2 = *(const uint4*)&Wc[(size_t)mrow2 * KI + k0 + mc];
      };
      auto commit = [&](int pb) {
        *(uint4*)&xs[pb * 2560 + xrow * 40 + xc] = xv;
        *(uint4*)&ms[pb * 6400 + mrow0 * 40 + mc] = m0;
        *(uint4*)&ms[pb * 6400 + mrow1 * 40 + mc] = m1;
        if (t < 128) *(uint4*)&ms[pb * 6400 + mrow2 * 40 + mc] = m2;
      };
      floatx4 acc[10];
#pragma unroll
      for (int jt = 0; jt < 10; ++jt) acc[jt] = (floatx4){0.f, 0.f, 0.f, 0.f};
      const int nsteps = KC >> 5;  // 9
      prefetch(kbase);
      commit(0);
      prefetch(kbase + 32);
      for (int s = 0; s < nsteps; ++s) {
        __syncthreads();
        if (s + 1 < nsteps) commit((s + 1) & 1);
        if (s + 2 < nsteps) prefetch(kbase + (s + 2) * 32);
        bf16x8 a = *(bf16x8*)&xs[(s & 1) * 2560 + (w * 16 + col) * 40 + quad * 8];
#pragma unroll
        for (int jt = 0; jt < 10; ++jt) {
          bf16x8 bb = *(bf16x8*)&ms[(s & 1) * 6400 + (jt * 16 + col) * 40 + quad * 8];
          acc[jt] = __builtin_amdgcn_mfma_f32_16x16x32_bf16(a, bb, acc[jt], 0, 0, 0);
        }
      }
#pragma unroll
      for (int jt = 0; jt < 10; ++jt)
#pragma unroll
        for (int r = 0; r < 4; ++r) {
          int b = b0 + w * 16 + quad * 4 + r;
          sp[((size_t)(blockIdx.x >> 3) * B + b) * JU + jt * 16 + col] = acc[jt][r];
        }
    }
    gsync();

    // ---- phase S: squash (2 b per block, sequential) ----
    for (int bi = 0; bi < 2; ++bi) {
      int b = blockIdx.x * 2 + bi;
      float s = 0.0f;
      if (t < JU) {
#pragma unroll
        for (int k = 0; k < NSPLIT; ++k) s += sp[((size_t)k * B + b) * JU + t];
        sv[t] = s;
      }
      __syncthreads();
      if (t < US) {
        float m = 0.0f;
#pragma unroll
        for (int j = 0; j < NU; ++j) {
          float q = sv[j * US + t];
          m += q * q;
        }
        fac[t] = sqrtf(m) / (BETAC + m);
      }
      __syncthreads();
      if (t < JU) {
        float val = s * fac[t & 15];
        vT[(size_t)t * B + b] = f2bf(val);
        if (it == 2) out[(size_t)b * JU + t] = val;
      }
      __syncthreads();
    }
    if (it == 2) return;
    gsync();

    // ---- phase U: b_update (288 items, grid-strided) ----
    for (int item = blockIdx.x; item < 288; item += gridDim.x) {
      const int bu = item >> 1;           // 0..143
      const int bs = item & 1;
      const int k = bu / 18;
      const int i0 = (bu - k * 18) * 64;
      const size_t ki0 = (size_t)k * IC + i0;
      __syncthreads();                    // LDS reuse across items
      uint4 xv, m0, m1, m2;
      auto prefetch = [&](int c0) {
        xv = *(const uint4*)&xT[(ki0 + xrow) * B + c0 + xc];
        m0 = *(const uint4*)&vT[(size_t)mrow0 * B + c0 + mc];
        m1 = *(const uint4*)&vT[(size_t)mrow1 * B + c0 + mc];
        if (t < 128) m2 = *(const uint4*)&vT[(size_t)mrow2 * B + c0 + mc];
      };
      auto commit = [&](int pb) {
        *(uint4*)&xs[pb * 2560 + xrow * 40 + xc] = xv;
        *(uint4*)&ms[pb * 6400 + mrow0 * 40 + mc] = m0;
        *(uint4*)&ms[pb * 6400 + mrow1 * 40 + mc] = m1;
        if (t < 128) *(uint4*)&ms[pb * 6400 + mrow2 * 40 + mc] = m2;
      };
      floatx4 acc[10];
#pragma unroll
      for (int jt = 0; jt < 10; ++jt) acc[jt] = (floatx4){0.f, 0.f, 0.f, 0.f};
      prefetch(bs * 256);
      commit(0);
      prefetch(bs * 256 + 32);
      for (int s = 0; s < 8; ++s) {
        __syncthreads();
        if (s + 1 < 8) commit((s + 1) & 1);
        if (s + 2 < 8) prefetch(bs * 256 + (s + 2) * 32);
        bf16x8 a = *(bf16x8*)&xs[(s & 1) * 2560 + (w * 16 + col) * 40 + quad * 8];
#pragma unroll
        for (int jt = 0; jt < 10; ++jt) {
          bf16x8 bb = *(bf16x8*)&ms[(s & 1) * 6400 + (jt * 16 + col) * 40 + quad * 8];
          acc[jt] = __builtin_amdgcn_mfma_f32_16x16x32_bf16(a, bb, acc[jt], 0, 0, 0);
        }
      }
      const int p = k * 2 + bs;
#pragma unroll
      for (int jt = 0; jt < 10; ++jt) {
#pragma unroll
        for (int r = 0; r < 4; ++r) {
          int i = i0 + w * 16 + quad * 4 + r;
          float wv = Wr[((size_t)k * IC + i) * JU + jt * 16 + col];
          float pr = wv * acc[jt][r];
          pr += __shfl_xor(pr, 1);
          pr += __shfl_xor(pr, 2);
          pr += __shfl_xor(pr, 4);
          pr += __shfl_xor(pr, 8);
          if (col == 0)
            bp[(size_t)p * (IC * NU) + jt * IC + i] = pr * (1.0f / (float)B);
        }
      }
    }
    gsync();

    // ---- phase C: softmax over i + fold c into Wc (160 items) ----
    if (blockIdx.x < 160) {
      const int ju = blockIdx.x;
      const int j = ju >> 4;
      for (int i = t; i < IC; i += 256) {
        float s = 0.0f;
#pragma unroll
        for (int p = 0; p < 16; ++p) s += bp[(size_t)p * (IC * NU) + j * IC + i];
        c_sh[i] = s;
      }
      __syncthreads();
      float m = -1e30f;
      for (int i = t; i < IC; i += 256) m = fmaxf(m, c_sh[i]);
      red[t] = m;
      __syncthreads();
      for (int o = 128; o > 0; o >>= 1) {
        if (t < o) red[t] = fmaxf(red[t], red[t + o]);
        __syncthreads();
      }
      float mx = red[0];
      __syncthreads();
      float sm = 0.0f;
      for (int i = t; i < IC; i += 256) {
        float e = __expf(c_sh[i] - mx);
        c_sh[i] = e;
        sm += e;
      }
      red[t] = sm;
      __syncthreads();
      for (int o = 128; o > 0; o >>= 1) {
        if (t < o) red[t] += red[t + o];
        __syncthreads();
      }
      float inv = 1.0f / red[0];
      for (int q = t; q < KI / 8; q += 256) {
        int ki = q * 8;
        int i = ki % IC;            // chunk never straddles k (IC % 8 == 0)
        uint4 wv = *(const uint4*)&Wt[(size_t)ju * KI + ki];
        float4 cA = make_float4(c_sh[i] * inv, c_sh[i + 1] * inv,
                                c_sh[i + 2] * inv, c_sh[i + 3] * inv);
        float4 cB = make_float4(c_sh[i + 4] * inv, c_sh[i + 5] * inv,
                                c_sh[i + 6] * inv, c_sh[i + 7] * inv);
        *(uint4*)&Wc[(size_t)ju * KI + ki] = scale8(wv, cA, cB);
      }
    }
    gsync();
  }
}

// ---------------------------------------------------------------------------
extern "C" void kernel_launch(void* const* d_in, const int* in_sizes, int n_in,
                              void* d_out, int out_size, void* d_ws,
                              size_t ws_size, hipStream_t stream) {
  const float* x = (const float*)d_in[0];   // (512, 8, 1152)
  const float* W = (const float*)d_in[1];   // (1152, 10, 16, 8)
  float* out = (float*)d_out;               // (512, 10, 16)

  // workspace layout (~42 MB; harness provides ~268 MB)
  char* pws = (char*)d_ws;
  float* bp = (float*)pws;                     pws += (size_t)16 * IC * NU * 4;
  float* sp = (float*)pws;                     pws += (size_t)NSPLIT * B * JU * 4;
  float* Wr = (float*)pws;                     pws += (size_t)KI * JU * 4;
  unsigned short* xb = (unsigned short*)pws;   pws += (size_t)B * KI * 2;
  unsigned short* xT = (unsigned short*)pws;   pws += (size_t)KI * B * 2;
  unsigned short* Wt = (unsigned short*)pws;   pws += (size_t)JU * KI * 2;
  unsigned short* Wc = (unsigned short*)pws;   pws += (size_t)JU * KI * 2;
  unsigned short* vT = (unsigned short*)pws;   pws += (size_t)JU * B * 2;
  int* gbar = (int*)pws;

  prep_kernel<<<1152 + 144, 256, 0, stream>>>(x, W, xb, xT, Wt, Wc, Wr, gbar);
  routing_kernel<<<256, 256, 0, stream>>>(xb, xT, Wt, Wc, Wr, sp, vT, bp, out,
                                          gbar);
}

// Round 4
// 158.924 us; speedup vs baseline: 2.5201x; 2.5201x over previous
//
#include <hip/hip_runtime.h>
#include <hip/hip_bf16.h>
#include <math.h>

#define B    512
#define INU  8
#define IC   1152
#define NU   10
#define US   16
#define JU   160            // NU*US
#define KI   9216           // INU*IC
#define BETAC 1.45f
#define NSPLIT 32
#define KC 288              // KI / NSPLIT; divides IC

typedef __attribute__((ext_vector_type(8))) __bf16 bf16x8;
typedef __attribute__((ext_vector_type(4))) float floatx4;

static __device__ __forceinline__ unsigned short f2bf(float f) {
  unsigned u = __builtin_bit_cast(unsigned, f);
  u = (u + 0x7fffu + ((u >> 16) & 1u)) >> 16;   // RNE
  return (unsigned short)u;
}
static __device__ __forceinline__ float bf2f(unsigned short h) {
  return __builtin_bit_cast(float, ((unsigned)h) << 16);
}
// 8 bf16 * 8 fp32 scale -> 8 bf16 (packed RNE converts)
static __device__ __forceinline__ uint4 scale8(uint4 wv, float4 cA, float4 cB) {
  union { uint4 u; unsigned short s[8]; } in;
  in.u = wv;
  union { uint4 u; __hip_bfloat162 h[4]; } o;
  o.h[0] = __float22bfloat162_rn(make_float2(bf2f(in.s[0]) * cA.x, bf2f(in.s[1]) * cA.y));
  o.h[1] = __float22bfloat162_rn(make_float2(bf2f(in.s[2]) * cA.z, bf2f(in.s[3]) * cA.w));
  o.h[2] = __float22bfloat162_rn(make_float2(bf2f(in.s[4]) * cB.x, bf2f(in.s[5]) * cB.y));
  o.h[3] = __float22bfloat162_rn(make_float2(bf2f(in.s[6]) * cB.z, bf2f(in.s[7]) * cB.w));
  return o.u;
}

// ---------------------------------------------------------------------------
// prep (one-time): blocks [0,1152): x -> xb bf16 [b][ki] + xT bf16 [ki][b]
// (64x64 LDS transpose). blocks [1152,1296): W LDS-tiled -> Wt bf16 [ju][ki]
// (MFMA B layout) + Wc = Wt * (1/IC) (iteration-0 scaled weights) + Wr fp32
// [ki][ju] (coalesced epilogue reads).
// ---------------------------------------------------------------------------
__global__ __launch_bounds__(256) void prep_kernel(
    const float* __restrict__ x, const float* __restrict__ W,
    unsigned short* __restrict__ xb, unsigned short* __restrict__ xT,
    unsigned short* __restrict__ Wt, unsigned short* __restrict__ Wc,
    float* __restrict__ Wr) {
  __shared__ float ts[32 * 322];    // 41.2 KB (x-part uses first 64*65)
  int id = blockIdx.x;
  int t = threadIdx.x;
  if (id < 1152) {
    int k0 = (id % 144) * 64;
    int b0 = (id / 144) * 64;
#pragma unroll
    for (int r = 0; r < 16; ++r) {
      int idx = t + 256 * r;
      int br = idx >> 6, kc = idx & 63;
      float v = x[(size_t)(b0 + br) * KI + k0 + kc];
      ts[br * 65 + kc] = v;
      xb[(size_t)(b0 + br) * KI + k0 + kc] = f2bf(v);
    }
    __syncthreads();
#pragma unroll
    for (int r = 0; r < 8; ++r) {
      int idx = t + 256 * r;            // 0..2047
      int kr = idx >> 5, bc = (idx & 31) * 2;
      unsigned lo = f2bf(ts[bc * 65 + kr]);
      unsigned hi = f2bf(ts[(bc + 1) * 65 + kr]);
      *(unsigned*)&xT[(size_t)(k0 + kr) * B + b0 + bc] = lo | (hi << 16);
    }
  } else {
    int wid = id - 1152;              // 0..143
    int i0 = (wid >> 2) * 32;         // 36 i-chunks
    int c0 = (wid & 3) * 320;         // 4 c-chunks of W's 1280-wide rows
#pragma unroll
    for (int r = 0; r < 20; ++r) {
      int q = t + 256 * r;            // < 5120 float2
      int il = q / 160, c = (q - il * 160) * 2;
      *(float2*)&ts[il * 322 + c] =
          *(const float2*)&W[(size_t)(i0 + il) * 1280 + c0 + c];
    }
    __syncthreads();
    {
      const float cinv = 1.0f / (float)IC;
      int il2 = (t & 15) * 2;
      for (int p = (t >> 4); p < 320; p += 16) {
        int c = c0 + p;
        int ju = c >> 3, k = c & 7;
        unsigned lo = f2bf(ts[il2 * 322 + p]);
        unsigned hi = f2bf(ts[(il2 + 1) * 322 + p]);
        *(unsigned*)&Wt[(size_t)ju * KI + k * IC + i0 + il2] = lo | (hi << 16);
        unsigned lo2 = f2bf(bf2f((unsigned short)lo) * cinv);
        unsigned hi2 = f2bf(bf2f((unsigned short)hi) * cinv);
        *(unsigned*)&Wc[(size_t)ju * KI + k * IC + i0 + il2] = lo2 | (hi2 << 16);
      }
    }
    int ju0 = c0 >> 3;
    for (int q = t; q < 8 * 32 * 40; q += 256) {
      int k = q / 1280;
      int il = (q / 40) & 31;
      int jl = q - (q / 40) * 40;
      Wr[((size_t)k * IC + i0 + il) * JU + ju0 + jl] = ts[il * 322 + jl * 8 + k];
    }
  }
}

// ---------------------------------------------------------------------------
// s_gemm (pure bf16 MFMA GEMM, j-split for 2 blocks/CU occupancy):
// sp[b][y][j0+..] = sum_{ki in chunk y} xb[b,ki] * Wc[j0+ju,ki]
// Grid: (8 b-tiles, NSPLIT k-chunks, 2 j-halves) x 256. 23 KB LDS, acc[5]
// -> 2 blocks/CU co-resident (2 waves/SIMD): one block's staging overlaps
// the other's MFMA phase (round-3 counters showed 1 wave/SIMD = latency-bound).
// ---------------------------------------------------------------------------
__global__ __launch_bounds__(256) void s_gemm_mfma(
    const unsigned short* __restrict__ xb, const unsigned short* __restrict__ Wc,
    float* __restrict__ sp) {
  int b0 = blockIdx.x * 64;
  int kbase = blockIdx.y * KC;
  int j0 = blockIdx.z * 80;           // j-half row offset
  int t = threadIdx.x;
  int w = t >> 6, lane = t & 63, col = lane & 15, quad = lane >> 4;
  __shared__ unsigned short xs[2][64 * 40];   // pad 40: <=2-way (free)
  __shared__ unsigned short ms[2][80 * 40];

  int xrow = t >> 2, xc = (t & 3) * 8;
  int mrow0 = t >> 2, mrow1 = 64 + (t >> 2);  // rows 64..79 by t<64
  int mc = (t & 3) * 8;

  uint4 xv, m0, m1;
  auto prefetch = [&](int k0) {
    xv = *(const uint4*)&xb[(size_t)(b0 + xrow) * KI + k0 + xc];
    m0 = *(const uint4*)&Wc[(size_t)(j0 + mrow0) * KI + k0 + mc];
    if (t < 64) m1 = *(const uint4*)&Wc[(size_t)(j0 + mrow1) * KI + k0 + mc];
  };
  auto commit = [&](int pb) {
    *(uint4*)&xs[pb][xrow * 40 + xc] = xv;
    *(uint4*)&ms[pb][mrow0 * 40 + mc] = m0;
    if (t < 64) *(uint4*)&ms[pb][mrow1 * 40 + mc] = m1;
  };
  floatx4 acc[5];
#pragma unroll
  for (int jt = 0; jt < 5; ++jt) acc[jt] = (floatx4){0.f, 0.f, 0.f, 0.f};
  const int nsteps = KC >> 5;  // 9
  prefetch(kbase);
  commit(0);
  prefetch(kbase + 32);
  for (int s = 0; s < nsteps; ++s) {
    __syncthreads();                       // buf[s&1] complete for all waves
    if (s + 1 < nsteps) commit((s + 1) & 1);
    if (s + 2 < nsteps) prefetch(kbase + (s + 2) * 32);
    bf16x8 a = *(bf16x8*)&xs[s & 1][(w * 16 + col) * 40 + quad * 8];
#pragma unroll
    for (int jt = 0; jt < 5; ++jt) {
      bf16x8 bb = *(bf16x8*)&ms[s & 1][(jt * 16 + col) * 40 + quad * 8];
      acc[jt] = __builtin_amdgcn_mfma_f32_16x16x32_bf16(a, bb, acc[jt], 0, 0, 0);
    }
  }
#pragma unroll
  for (int jt = 0; jt < 5; ++jt)
#pragma unroll
    for (int r = 0; r < 4; ++r) {
      int b = b0 + w * 16 + quad * 4 + r;
      sp[((size_t)b * NSPLIT + blockIdx.y) * JU + j0 + jt * 16 + col] = acc[jt][r];
    }
}

// ---------------------------------------------------------------------------
// squash: s[b][ju] = sum_y sp[b][y][ju] (contiguous 20.5 KB per block);
// msq over j (axis=1 quirk, faithful); v -> vT bf16 [ju][b]; out fp32 on
// last iter. Grid: 512 x 192.
// ---------------------------------------------------------------------------
__global__ __launch_bounds__(192) void squash_kernel(
    const float* __restrict__ sp, unsigned short* __restrict__ vT,
    float* __restrict__ out) {
  int b = blockIdx.x;
  int t = threadIdx.x;
  __shared__ float sv[JU];
  __shared__ float fac[US];
  float s = 0.0f;
  if (t < JU) {
#pragma unroll
    for (int k = 0; k < NSPLIT; ++k) s += sp[((size_t)b * NSPLIT + k) * JU + t];
    sv[t] = s;
  }
  __syncthreads();
  if (t < US) {
    float m = 0.0f;
#pragma unroll
    for (int j = 0; j < NU; ++j) {
      float q = sv[j * US + t];
      m += q * q;
    }
    fac[t] = sqrtf(m) / (BETAC + m);
  }
  __syncthreads();
  if (t < JU) {
    float val = s * fac[t & 15];
    vT[(size_t)t * B + b] = f2bf(val);
    if (out) out[(size_t)b * JU + t] = val;
  }
}

// ---------------------------------------------------------------------------
// b_update (MFMA, j-split for occupancy):
// R[ki,ju] = sum_b xT[ki,b]*vT[ju,b] (K=b, split 2);
// bp[p][j][i] = (1/B) sum_u Wr[ki][ju]*R (16-lane shfl reduce, u=lane&15).
// Grid: (144 ki-tiles, 2 b-halves, 2 j-halves) x 256. 23 KB LDS, acc[5].
// Deterministic slice writes, no atomics, no fences.
// ---------------------------------------------------------------------------
__global__ __launch_bounds__(256) void b_update_mfma(
    const unsigned short* __restrict__ xT, const unsigned short* __restrict__ vT,
    const float* __restrict__ Wr, float* __restrict__ bp) {
  int k = blockIdx.x / 18;
  int i0 = (blockIdx.x - k * 18) * 64;
  int bs = blockIdx.y;
  int j0 = blockIdx.z * 80;
  size_t ki0 = (size_t)k * IC + i0;
  int t = threadIdx.x;
  int w = t >> 6, lane = t & 63, col = lane & 15, quad = lane >> 4;
  __shared__ unsigned short xs[2][64 * 40];
  __shared__ unsigned short vs[2][80 * 40];
  int xrow = t >> 2, xc = (t & 3) * 8;
  int mrow0 = t >> 2, mrow1 = 64 + (t >> 2);
  int mc = (t & 3) * 8;
  uint4 xv, m0, m1;
  auto prefetch = [&](int c0) {
    xv = *(const uint4*)&xT[(ki0 + xrow) * B + c0 + xc];
    m0 = *(const uint4*)&vT[(size_t)(j0 + mrow0) * B + c0 + mc];
    if (t < 64) m1 = *(const uint4*)&vT[(size_t)(j0 + mrow1) * B + c0 + mc];
  };
  auto commit = [&](int pb) {
    *(uint4*)&xs[pb][xrow * 40 + xc] = xv;
    *(uint4*)&vs[pb][mrow0 * 40 + mc] = m0;
    if (t < 64) *(uint4*)&vs[pb][mrow1 * 40 + mc] = m1;
  };
  floatx4 acc[5];
#pragma unroll
  for (int jt = 0; jt < 5; ++jt) acc[jt] = (floatx4){0.f, 0.f, 0.f, 0.f};
  prefetch(bs * 256);
  commit(0);
  prefetch(bs * 256 + 32);
  for (int s = 0; s < 8; ++s) {
    __syncthreads();
    if (s + 1 < 8) commit((s + 1) & 1);
    if (s + 2 < 8) prefetch(bs * 256 + (s + 2) * 32);
    bf16x8 a = *(bf16x8*)&xs[s & 1][(w * 16 + col) * 40 + quad * 8];
#pragma unroll
    for (int jt = 0; jt < 5; ++jt) {
      bf16x8 bb = *(bf16x8*)&vs[s & 1][(jt * 16 + col) * 40 + quad * 8];
      acc[jt] = __builtin_amdgcn_mfma_f32_16x16x32_bf16(a, bb, acc[jt], 0, 0, 0);
    }
  }
  int p = k * 2 + bs;
  int jb = blockIdx.z * 5;            // bp j offset
#pragma unroll
  for (int jt = 0; jt < 5; ++jt) {
#pragma unroll
    for (int r = 0; r < 4; ++r) {
      int i = i0 + w * 16 + quad * 4 + r;
      float wv = Wr[((size_t)k * IC + i) * JU + j0 + jt * 16 + col];
      float pr = wv * acc[jt][r];
      pr += __shfl_xor(pr, 1);
      pr += __shfl_xor(pr, 2);
      pr += __shfl_xor(pr, 4);
      pr += __shfl_xor(pr, 8);
      if (col == 0)
        bp[(size_t)p * (IC * NU) + (jb + jt) * IC + i] = pr * (1.0f / (float)B);
    }
  }
}

// ---------------------------------------------------------------------------
// softmax_scale: bij[j][i] = sum_p bp[p][j][i]; c[j][i] = softmax_i;
// then write Wc[ju][ki] = bf16(Wt[ju][ki] * c[j, i(ki)]) for the next
// routing iteration. One block per ju row (softmax recomputed redundantly
// per block — 73 KB of L2-hot bp reads; Wc row writes fully coalesced).
// Grid: 160 x 256.
// ---------------------------------------------------------------------------
__global__ __launch_bounds__(256) void softmax_scale_kernel(
    const float* __restrict__ bp, const unsigned short* __restrict__ Wt,
    unsigned short* __restrict__ Wc) {
  int ju = blockIdx.x;          // 0..159
  int j = ju >> 4;
  int t = threadIdx.x;
  __shared__ float c[IC];
  __shared__ float red[256];
  for (int i = t; i < IC; i += 256) {
    float s = 0.0f;
#pragma unroll
    for (int p = 0; p < 16; ++p) s += bp[(size_t)p * (IC * NU) + j * IC + i];
    c[i] = s;
  }
  __syncthreads();
  float m = -1e30f;
  for (int i = t; i < IC; i += 256) m = fmaxf(m, c[i]);
  red[t] = m;
  __syncthreads();
  for (int o = 128; o > 0; o >>= 1) {
    if (t < o) red[t] = fmaxf(red[t], red[t + o]);
    __syncthreads();
  }
  float mx = red[0];
  __syncthreads();
  float sm = 0.0f;
  for (int i = t; i < IC; i += 256) {
    float e = __expf(c[i] - mx);
    c[i] = e;
    sm += e;
  }
  red[t] = sm;
  __syncthreads();
  for (int o = 128; o > 0; o >>= 1) {
    if (t < o) red[t] += red[t + o];
    __syncthreads();
  }
  float inv = 1.0f / red[0];
  // write one Wc row (9216 bf16 = 1152 x uint4), fully coalesced
  for (int q = t; q < KI / 8; q += 256) {
    int ki = q * 8;
    int i = ki % IC;            // chunk never straddles k (IC % 8 == 0)
    uint4 wv = *(const uint4*)&Wt[(size_t)ju * KI + ki];
    float4 cA = make_float4(c[i] * inv, c[i + 1] * inv, c[i + 2] * inv, c[i + 3] * inv);
    float4 cB = make_float4(c[i + 4] * inv, c[i + 5] * inv, c[i + 6] * inv, c[i + 7] * inv);
    *(uint4*)&Wc[(size_t)ju * KI + ki] = scale8(wv, cA, cB);
  }
}

// ---------------------------------------------------------------------------
extern "C" void kernel_launch(void* const* d_in, const int* in_sizes, int n_in,
                              void* d_out, int out_size, void* d_ws,
                              size_t ws_size, hipStream_t stream) {
  const float* x = (const float*)d_in[0];   // (512, 8, 1152)
  const float* W = (const float*)d_in[1];   // (1152, 10, 16, 8)
  float* out = (float*)d_out;               // (512, 10, 16)

  // workspace layout (~42 MB; harness provides ~268 MB)
  char* pws = (char*)d_ws;
  float* bp = (float*)pws;                     pws += (size_t)16 * IC * NU * 4;
  float* sp = (float*)pws;                     pws += (size_t)NSPLIT * B * JU * 4;
  float* Wr = (float*)pws;                     pws += (size_t)KI * JU * 4;
  unsigned short* xb = (unsigned short*)pws;   pws += (size_t)B * KI * 2;
  unsigned short* xT = (unsigned short*)pws;   pws += (size_t)KI * B * 2;
  unsigned short* Wt = (unsigned short*)pws;   pws += (size_t)JU * KI * 2;
  unsigned short* Wc = (unsigned short*)pws;   pws += (size_t)JU * KI * 2;
  unsigned short* vT = (unsigned short*)pws;

  prep_kernel<<<1152 + 144, 256, 0, stream>>>(x, W, xb, xT, Wt, Wc, Wr);

  for (int it = 0; it < 3; ++it) {
    s_gemm_mfma<<<dim3(8, NSPLIT, 2), 256, 0, stream>>>(xb, Wc, sp);
    squash_kernel<<<B, 192, 0, stream>>>(sp, vT, (it == 2) ? out : nullptr);
    if (it < 2) {
      b_update_mfma<<<dim3(144, 2, 2), 256, 0, stream>>>(xT, vT, Wr, bp);
      softmax_scale_kernel<<<160, 256, 0, stream>>>(bp, Wt, Wc);
    }
  }
}